// Round 2
// baseline (687.551 us; speedup 1.0000x reference)
//
#include <hip/hip_runtime.h>
#include <hip/hip_bf16.h>
#include <math.h>

// Problem constants (from reference): B=4, T=4096, D=1024, hidden=4D.
#define B_SZ 4
#define T_SZ 4096
#define D_SZ 1024
#define H_SZ 4096
#define CHUNK 32
#define NCHUNK (T_SZ / CHUNK)   // 128
#define LN_EPS 1e-5f

using frag8 = __attribute__((ext_vector_type(8))) short;   // 8 x bf16 (4 VGPRs)
using f32x4 = __attribute__((ext_vector_type(4))) float;   // 4 x f32 acc

__device__ __forceinline__ float gelu_exact(float x) {
  return 0.5f * x * (1.0f + erff(x * 0.70710678118654752f));
}

__device__ __forceinline__ unsigned short f2bf(float f) {
  unsigned u = __float_as_uint(f);
  u += 0x7fffu + ((u >> 16) & 1u);   // round-to-nearest-even
  return (unsigned short)(u >> 16);
}

// Block (256 threads) reduction with broadcast. `red` is 4-float LDS.
__device__ __forceinline__ float blockReduceSum(float v, float* red) {
#pragma unroll
  for (int o = 32; o > 0; o >>= 1) v += __shfl_xor(v, o, 64);
  int w = threadIdx.x >> 6;
  if ((threadIdx.x & 63) == 0) red[w] = v;
  __syncthreads();
  float t = red[0] + red[1] + red[2] + red[3];
  __syncthreads();   // protect LDS for next call
  return t;
}

// ---------------------------------------------------------------------------
// Kernel A: per (b, time-chunk): LN1 + gelu + in-chunk inclusive cumsum.
// partial[b,t,:] = x + h + valid * localcum ; csum[b,c,:] = chunk sum of g.
// `partial` is d_out (the residual stream lives in the output buffer).
// ---------------------------------------------------------------------------
__global__ __launch_bounds__(256) void attn_phase1(
    const float* __restrict__ x, const int* __restrict__ lengths,
    const float* __restrict__ w1, float* __restrict__ partial,
    float* __restrict__ csum) {
  __shared__ float red[4];
  int b = blockIdx.x / NCHUNK;
  int c = blockIdx.x % NCHUNK;
  int tid = threadIdx.x;
  int len = lengths[b];
  float4 w = ((const float4*)w1)[tid];
  float run0 = 0.f, run1 = 0.f, run2 = 0.f, run3 = 0.f;
  for (int i = 0; i < CHUNK; ++i) {
    int t = c * CHUNK + i;
    size_t row = ((size_t)b * T_SZ + t) * D_SZ;
    float4 v = ((const float4*)(x + row))[tid];
    float s = v.x + v.y + v.z + v.w;
    s = blockReduceSum(s, red);
    float mu = s * (1.0f / D_SZ);
    float dx = v.x - mu, dy = v.y - mu, dz = v.z - mu, dw = v.w - mu;
    float s2 = dx * dx + dy * dy + dz * dz + dw * dw;
    s2 = blockReduceSum(s2, red);
    float rstd = rsqrtf(s2 * (1.0f / D_SZ) + LN_EPS);
    bool valid = t < len;
    float hx = dx * rstd * w.x, hy = dy * rstd * w.y;
    float hz = dz * rstd * w.z, hw = dw * rstd * w.w;
    if (valid) {
      run0 += gelu_exact(hx); run1 += gelu_exact(hy);
      run2 += gelu_exact(hz); run3 += gelu_exact(hw);
    }
    float4 p;
    p.x = v.x + hx + (valid ? run0 : 0.f);
    p.y = v.y + hy + (valid ? run1 : 0.f);
    p.z = v.z + hz + (valid ? run2 : 0.f);
    p.w = v.w + hw + (valid ? run3 : 0.f);
    ((float4*)(partial + row))[tid] = p;
  }
  float4 cs; cs.x = run0; cs.y = run1; cs.z = run2; cs.w = run3;
  ((float4*)(csum + ((size_t)b * NCHUNK + c) * D_SZ))[tid] = cs;
}

// ---------------------------------------------------------------------------
// Kernel B: in-place exclusive scan of chunk sums along c, per (b,d).
// ---------------------------------------------------------------------------
__global__ __launch_bounds__(256) void chunk_scan(float* __restrict__ csum) {
  int idx = blockIdx.x * 256 + threadIdx.x;   // 0 .. B*D-1
  int b = idx >> 10;
  int d = idx & (D_SZ - 1);
  float* p = csum + (size_t)b * NCHUNK * D_SZ + d;
  float acc = 0.f;
#pragma unroll 8
  for (int c = 0; c < NCHUNK; ++c) {
    float t = p[(size_t)c * D_SZ];
    p[(size_t)c * D_SZ] = acc;
    acc += t;
  }
}

// ---------------------------------------------------------------------------
// Kernel C: xres = partial + valid*offset (in place on d_out), then LN2 -> h2.
// ---------------------------------------------------------------------------
__global__ __launch_bounds__(256) void attn_phase2_ln2(
    float* __restrict__ xres, const float* __restrict__ csum,
    const int* __restrict__ lengths, const float* __restrict__ w2,
    unsigned short* __restrict__ h2) {
  __shared__ float red[4];
  int t = blockIdx.x & (T_SZ - 1);
  int b = blockIdx.x >> 12;
  int tid = threadIdx.x;
  bool valid = t < lengths[b];
  int c = t / CHUNK;
  size_t row = ((size_t)b * T_SZ + t) * D_SZ;
  float4 v = ((const float4*)(xres + row))[tid];
  if (valid) {
    float4 o = ((const float4*)(csum + ((size_t)b * NCHUNK + c) * D_SZ))[tid];
    v.x += o.x; v.y += o.y; v.z += o.z; v.w += o.w;
  }
  ((float4*)(xres + row))[tid] = v;
  float s = v.x + v.y + v.z + v.w;
  s = blockReduceSum(s, red);
  float mu = s * (1.0f / D_SZ);
  float dx = v.x - mu, dy = v.y - mu, dz = v.z - mu, dw = v.w - mu;
  float s2 = dx * dx + dy * dy + dz * dz + dw * dw;
  s2 = blockReduceSum(s2, red);
  float rstd = rsqrtf(s2 * (1.0f / D_SZ) + LN_EPS);
  float4 w = ((const float4*)w2)[tid];
  ushort4 hq;
  hq.x = f2bf(dx * rstd * w.x);
  hq.y = f2bf(dy * rstd * w.y);
  hq.z = f2bf(dz * rstd * w.z);
  hq.w = f2bf(dw * rstd * w.w);
  ((ushort4*)(h2 + row))[tid] = hq;
}

// ---------------------------------------------------------------------------
// Transpose + fp32->bf16 convert: src (R x C) row-major -> dst (C x R) bf16.
// ---------------------------------------------------------------------------
__global__ __launch_bounds__(256) void transpose_f32_to_bf16(
    const float* __restrict__ src, unsigned short* __restrict__ dst,
    int R, int C) {
  __shared__ float tile[32][33];
  int bx = blockIdx.x * 32;   // C base
  int by = blockIdx.y * 32;   // R base
  int tx = threadIdx.x & 31;
  int ty = threadIdx.x >> 5;  // 0..7
#pragma unroll
  for (int i = 0; i < 32; i += 8)
    tile[ty + i][tx] = src[(size_t)(by + ty + i) * C + bx + tx];
  __syncthreads();
#pragma unroll
  for (int i = 0; i < 32; i += 8)
    dst[(size_t)(bx + ty + i) * R + by + tx] = f2bf(tile[tx][ty + i]);
}

// ---------------------------------------------------------------------------
// m97-style bf16 GEMM: C[rows,N] = A[rows,K] * Bt[N,K]^T, 128x128 tile,
// 4 waves. epi==0: out_bf16 = bf16(gelu(C)); epi==1: out_f32 = resid + C.
// ---------------------------------------------------------------------------
__device__ __forceinline__ void gld_lds16(const unsigned short* g,
                                          unsigned short* l) {
  __builtin_amdgcn_global_load_lds(
      (const __attribute__((address_space(1))) unsigned int*)g,
      (__attribute__((address_space(3))) unsigned int*)l, 16, 0, 0);
}

__global__ __launch_bounds__(256) void gemm_bt(
    const unsigned short* __restrict__ A, const unsigned short* __restrict__ Bt,
    int N, int K,
    const float* __restrict__ resid, float* __restrict__ outf,
    unsigned short* __restrict__ outb, int epi) {
  __shared__ __align__(16) unsigned short As[128 * 32];
  __shared__ __align__(16) unsigned short Bs[128 * 32];
  int tid = threadIdx.x;
  int lane = tid & 63;
  int wave = tid >> 6;
  int bm = blockIdx.y * 128;
  int bn = blockIdx.x * 128;
  int wm = (wave & 1) * 64;
  int wn = (wave >> 1) * 64;
  int quad = lane >> 4;
  int r16 = lane & 15;

  f32x4 acc[4][4] = {};

  int ar = tid >> 2;           // 0..63 (row within half-tile)
  int ac = (tid & 3) * 8;      // 0,8,16,24 (k within 32)
  const unsigned short* Ag = A + (size_t)(bm + ar) * K + ac;
  const unsigned short* Bg = Bt + (size_t)(bn + ar) * K + ac;
  unsigned short* AsW = &As[ar * 32 + ac];
  unsigned short* BsW = &Bs[ar * 32 + ac];

  for (int k0 = 0; k0 < K; k0 += 32) {
    gld_lds16(Ag + k0, AsW);
    gld_lds16(Ag + (size_t)64 * K + k0, AsW + 64 * 32);
    gld_lds16(Bg + k0, BsW);
    gld_lds16(Bg + (size_t)64 * K + k0, BsW + 64 * 32);
    __syncthreads();   // drains vmcnt (global_load_lds) + orders LDS
    frag8 af[4], bfr[4];
#pragma unroll
    for (int tm = 0; tm < 4; ++tm)
      af[tm] = *(const frag8*)&As[(wm + tm * 16 + r16) * 32 + quad * 8];
#pragma unroll
    for (int tn = 0; tn < 4; ++tn)
      bfr[tn] = *(const frag8*)&Bs[(wn + tn * 16 + r16) * 32 + quad * 8];
#pragma unroll
    for (int tm = 0; tm < 4; ++tm)
#pragma unroll
      for (int tn = 0; tn < 4; ++tn)
        acc[tm][tn] = __builtin_amdgcn_mfma_f32_16x16x32_bf16(
            af[tm], bfr[tn], acc[tm][tn], 0, 0, 0);
    __syncthreads();   // protect LDS before next stage
  }

  if (epi == 0) {
#pragma unroll
    for (int tm = 0; tm < 4; ++tm) {
#pragma unroll
      for (int tn = 0; tn < 4; ++tn) {
        int m0 = bm + wm + tm * 16 + quad * 4;
        int n = bn + wn + tn * 16 + r16;
#pragma unroll
        for (int r = 0; r < 4; ++r)
          outb[(size_t)(m0 + r) * N + n] = f2bf(gelu_exact(acc[tm][tn][r]));
      }
    }
  } else {
#pragma unroll
    for (int tm = 0; tm < 4; ++tm) {
#pragma unroll
      for (int tn = 0; tn < 4; ++tn) {
        int m0 = bm + wm + tm * 16 + quad * 4;
        int n = bn + wn + tn * 16 + r16;
#pragma unroll
        for (int r = 0; r < 4; ++r)
          outf[(size_t)(m0 + r) * N + n] =
              resid[(size_t)(m0 + r) * N + n] + acc[tm][tn][r];
      }
    }
  }
}

// ---------------------------------------------------------------------------
extern "C" void kernel_launch(void* const* d_in, const int* in_sizes, int n_in,
                              void* d_out, int out_size, void* d_ws,
                              size_t ws_size, hipStream_t stream) {
  const float* x = (const float*)d_in[0];
  const int* lengths = (const int*)d_in[1];
  const float* ln1_w = (const float*)d_in[2];
  const float* ln2_w = (const float*)d_in[3];
  const float* Wfc = (const float*)d_in[4];
  const float* Wproj = (const float*)d_in[5];
  float* out = (float*)d_out;   // doubles as the xres residual-stream buffer

  // Workspace layout — fixed 50 MiB + act slice sized from ws_size.
  char* ws = (char*)d_ws;
  size_t off = 0;
  float* csum = (float*)(ws + off);
  off += (size_t)B_SZ * NCHUNK * D_SZ * sizeof(float);          // 2 MiB
  unsigned short* wfcb = (unsigned short*)(ws + off);
  off += (size_t)D_SZ * H_SZ * sizeof(unsigned short);          // 8 MiB
  unsigned short* wprojb = (unsigned short*)(ws + off);
  off += (size_t)H_SZ * D_SZ * sizeof(unsigned short);          // 8 MiB
  unsigned short* h2 = (unsigned short*)(ws + off);
  off += (size_t)B_SZ * T_SZ * D_SZ * sizeof(unsigned short);   // 32 MiB
  unsigned short* act = (unsigned short*)(ws + off);            // slice buffer

  const int M = B_SZ * T_SZ;                       // 16384
  const size_t tileBytes = 128ull * H_SZ * sizeof(unsigned short);  // 1 MiB
  size_t avail = (ws_size > off) ? (ws_size - off) : 0;
  int sliceTiles = (int)(avail / tileBytes);
  if (sliceTiles < 1) sliceTiles = 1;              // last-resort (ws too small)
  int sliceM = sliceTiles * 128;
  if (sliceM > M) sliceM = M;

  attn_phase1<<<B_SZ * NCHUNK, 256, 0, stream>>>(x, lengths, ln1_w, out, csum);
  chunk_scan<<<(B_SZ * D_SZ) / 256, 256, 0, stream>>>(csum);
  attn_phase2_ln2<<<B_SZ * T_SZ, 256, 0, stream>>>(out, csum, lengths, ln2_w, h2);
  transpose_f32_to_bf16<<<dim3(H_SZ / 32, D_SZ / 32), 256, 0, stream>>>(
      Wfc, wfcb, D_SZ, H_SZ);
  transpose_f32_to_bf16<<<dim3(D_SZ / 32, H_SZ / 32), 256, 0, stream>>>(
      Wproj, wprojb, H_SZ, D_SZ);

  for (int m0 = 0; m0 < M; m0 += sliceM) {
    int rows = (M - m0 < sliceM) ? (M - m0) : sliceM;
    // act = bf16(gelu(h2[m0:m0+rows] @ Wfc))
    gemm_bt<<<dim3(H_SZ / 128, rows / 128), 256, 0, stream>>>(
        h2 + (size_t)m0 * D_SZ, wfcb, H_SZ, D_SZ, nullptr, nullptr, act, 0);
    // out[m0:m0+rows] = out[m0:m0+rows] + act @ Wproj
    gemm_bt<<<dim3(D_SZ / 128, rows / 128), 256, 0, stream>>>(
        act, wprojb, D_SZ, H_SZ, out + (size_t)m0 * D_SZ,
        out + (size_t)m0 * D_SZ, nullptr, 1);
  }
}

// Round 3
// 670.999 us; speedup vs baseline: 1.0247x; 1.0247x over previous
//
#include <hip/hip_runtime.h>
#include <hip/hip_bf16.h>
#include <math.h>

// Problem constants (from reference): B=4, T=4096, D=1024, hidden=4D.
#define B_SZ 4
#define T_SZ 4096
#define D_SZ 1024
#define H_SZ 4096
#define CHUNK 16
#define NCHUNK (T_SZ / CHUNK)   // 256
#define LN_EPS 1e-5f

using frag8 = __attribute__((ext_vector_type(8))) short;   // 8 x bf16 (4 VGPRs)
using f32x4 = __attribute__((ext_vector_type(4))) float;   // 4 x f32 acc

__device__ __forceinline__ float gelu_exact(float x) {
  return 0.5f * x * (1.0f + erff(x * 0.70710678118654752f));
}

// tanh-form gelu: x*sigmoid(2u) = x - x/(e^{2u}+1), overflow-safe
// (e=inf -> x; e=0 -> 0). ~8 VALU ops vs ~25 for erff.
__device__ __forceinline__ float gelu_fast(float x) {
  float u2 = 1.5957691216057308f * (x + 0.044715f * x * x * x);  // 2*0.7978..*
  float e = __expf(u2);
  return x - x * __builtin_amdgcn_rcpf(e + 1.0f);
}

__device__ __forceinline__ unsigned short f2bf(float f) {
  unsigned u = __float_as_uint(f);
  u += 0x7fffu + ((u >> 16) & 1u);   // round-to-nearest-even
  return (unsigned short)(u >> 16);
}

// ---------------------------------------------------------------------------
// LN1 statistics: one block per (b,t) row; fused sum+sumsq reduction.
// stats[b*T+t] = {mu, rstd}
// ---------------------------------------------------------------------------
__global__ __launch_bounds__(256) void ln_stats(
    const float* __restrict__ x, float2* __restrict__ stats) {
  __shared__ float red[8];
  int tid = threadIdx.x;
  size_t row = (size_t)blockIdx.x * D_SZ;
  float4 v = ((const float4*)(x + row))[tid];
  float s = v.x + v.y + v.z + v.w;
  float q = v.x * v.x + v.y * v.y + v.z * v.z + v.w * v.w;
#pragma unroll
  for (int o = 32; o > 0; o >>= 1) {
    s += __shfl_xor(s, o, 64);
    q += __shfl_xor(q, o, 64);
  }
  int w = tid >> 6;
  if ((tid & 63) == 0) { red[w * 2] = s; red[w * 2 + 1] = q; }
  __syncthreads();
  if (tid == 0) {
    s = red[0] + red[2] + red[4] + red[6];
    q = red[1] + red[3] + red[5] + red[7];
    float mu = s * (1.0f / D_SZ);
    float var = q * (1.0f / D_SZ) - mu * mu;
    float2 st; st.x = mu; st.y = rsqrtf(var + LN_EPS);
    stats[blockIdx.x] = st;
  }
}

// ---------------------------------------------------------------------------
// Kernel A: per (b, time-chunk): LN1(from stats) + gelu + in-chunk cumsum.
// Barrier-free streaming. partial = d_out (residual stream lives there).
// ---------------------------------------------------------------------------
__global__ __launch_bounds__(256) void attn_phase1(
    const float* __restrict__ x, const float2* __restrict__ stats,
    const int* __restrict__ lengths, const float* __restrict__ w1,
    float* __restrict__ partial, float* __restrict__ csum) {
  int b = blockIdx.x >> 8;          // NCHUNK = 256
  int c = blockIdx.x & (NCHUNK - 1);
  int tid = threadIdx.x;
  int len = lengths[b];
  float4 w = ((const float4*)w1)[tid];
  float run0 = 0.f, run1 = 0.f, run2 = 0.f, run3 = 0.f;
#pragma unroll 4
  for (int i = 0; i < CHUNK; ++i) {
    int t = c * CHUNK + i;
    size_t row = ((size_t)b * T_SZ + t) * D_SZ;
    float4 v = ((const float4*)(x + row))[tid];
    float2 st = stats[b * T_SZ + t];   // wave-uniform -> scalar load
    bool valid = t < len;
    float hx = (v.x - st.x) * st.y * w.x, hy = (v.y - st.x) * st.y * w.y;
    float hz = (v.z - st.x) * st.y * w.z, hw = (v.w - st.x) * st.y * w.w;
    if (valid) {
      run0 += gelu_exact(hx); run1 += gelu_exact(hy);
      run2 += gelu_exact(hz); run3 += gelu_exact(hw);
    }
    float4 p;
    p.x = v.x + hx + (valid ? run0 : 0.f);
    p.y = v.y + hy + (valid ? run1 : 0.f);
    p.z = v.z + hz + (valid ? run2 : 0.f);
    p.w = v.w + hw + (valid ? run3 : 0.f);
    ((float4*)(partial + row))[tid] = p;
  }
  float4 cs; cs.x = run0; cs.y = run1; cs.z = run2; cs.w = run3;
  ((float4*)(csum + ((size_t)b * NCHUNK + c) * D_SZ))[tid] = cs;
}

// ---------------------------------------------------------------------------
// Kernel B: in-place exclusive scan of chunk sums along c, per (b,d).
// ---------------------------------------------------------------------------
__global__ __launch_bounds__(256) void chunk_scan(float* __restrict__ csum) {
  int idx = blockIdx.x * 256 + threadIdx.x;   // 0 .. B*D-1
  int b = idx >> 10;
  int d = idx & (D_SZ - 1);
  float* p = csum + (size_t)b * NCHUNK * D_SZ + d;
  float acc = 0.f;
#pragma unroll 8
  for (int c = 0; c < NCHUNK; ++c) {
    float t = p[(size_t)c * D_SZ];
    p[(size_t)c * D_SZ] = acc;
    acc += t;
  }
}

// ---------------------------------------------------------------------------
// Kernel C: xres = partial + valid*offset (in place on d_out), then LN2 -> h2.
// Fused sum+sumsq single reduction.
// ---------------------------------------------------------------------------
__global__ __launch_bounds__(256) void attn_phase2_ln2(
    float* __restrict__ xres, const float* __restrict__ csum,
    const int* __restrict__ lengths, const float* __restrict__ w2,
    unsigned short* __restrict__ h2) {
  __shared__ float red[8];
  int t = blockIdx.x & (T_SZ - 1);
  int b = blockIdx.x >> 12;
  int tid = threadIdx.x;
  bool valid = t < lengths[b];
  int c = t / CHUNK;
  size_t row = ((size_t)b * T_SZ + t) * D_SZ;
  float4 v = ((const float4*)(xres + row))[tid];
  if (valid) {
    float4 o = ((const float4*)(csum + ((size_t)b * NCHUNK + c) * D_SZ))[tid];
    v.x += o.x; v.y += o.y; v.z += o.z; v.w += o.w;
  }
  ((float4*)(xres + row))[tid] = v;
  float s = v.x + v.y + v.z + v.w;
  float q = v.x * v.x + v.y * v.y + v.z * v.z + v.w * v.w;
#pragma unroll
  for (int o = 32; o > 0; o >>= 1) {
    s += __shfl_xor(s, o, 64);
    q += __shfl_xor(q, o, 64);
  }
  int wv = tid >> 6;
  if ((tid & 63) == 0) { red[wv * 2] = s; red[wv * 2 + 1] = q; }
  __syncthreads();
  s = red[0] + red[2] + red[4] + red[6];
  q = red[1] + red[3] + red[5] + red[7];
  float mu = s * (1.0f / D_SZ);
  float var = q * (1.0f / D_SZ) - mu * mu;
  float rstd = rsqrtf(var + LN_EPS);
  float4 w = ((const float4*)w2)[tid];
  ushort4 hq;
  hq.x = f2bf((v.x - mu) * rstd * w.x);
  hq.y = f2bf((v.y - mu) * rstd * w.y);
  hq.z = f2bf((v.z - mu) * rstd * w.z);
  hq.w = f2bf((v.w - mu) * rstd * w.w);
  ((ushort4*)(h2 + row))[tid] = hq;
}

// ---------------------------------------------------------------------------
// Transpose + fp32->bf16 convert: src (R x C) row-major -> dst (C x R) bf16.
// ---------------------------------------------------------------------------
__global__ __launch_bounds__(256) void transpose_f32_to_bf16(
    const float* __restrict__ src, unsigned short* __restrict__ dst,
    int R, int C) {
  __shared__ float tile[32][33];
  int bx = blockIdx.x * 32;   // C base
  int by = blockIdx.y * 32;   // R base
  int tx = threadIdx.x & 31;
  int ty = threadIdx.x >> 5;  // 0..7
#pragma unroll
  for (int i = 0; i < 32; i += 8)
    tile[ty + i][tx] = src[(size_t)(by + ty + i) * C + bx + tx];
  __syncthreads();
#pragma unroll
  for (int i = 0; i < 32; i += 8)
    dst[(size_t)(bx + ty + i) * R + by + tx] = f2bf(tile[tx][ty + i]);
}

// ---------------------------------------------------------------------------
// m97-style bf16 GEMM: C[rows,N] = A[rows,K] * Bt[N,K]^T, 128x128 tile,
// 4 waves. epi==0: out_bf16 = bf16(gelu_fast(C)); epi==1: out_f32 = resid + C.
// ---------------------------------------------------------------------------
__device__ __forceinline__ void gld_lds16(const unsigned short* g,
                                          unsigned short* l) {
  __builtin_amdgcn_global_load_lds(
      (const __attribute__((address_space(1))) unsigned int*)g,
      (__attribute__((address_space(3))) unsigned int*)l, 16, 0, 0);
}

__global__ __launch_bounds__(256) void gemm_bt(
    const unsigned short* __restrict__ A, const unsigned short* __restrict__ Bt,
    int N, int K,
    const float* __restrict__ resid, float* __restrict__ outf,
    unsigned short* __restrict__ outb, int epi) {
  __shared__ __align__(16) unsigned short As[128 * 32];
  __shared__ __align__(16) unsigned short Bs[128 * 32];
  int tid = threadIdx.x;
  int lane = tid & 63;
  int wave = tid >> 6;
  int bm = blockIdx.y * 128;
  int bn = blockIdx.x * 128;
  int wm = (wave & 1) * 64;
  int wn = (wave >> 1) * 64;
  int quad = lane >> 4;
  int r16 = lane & 15;

  f32x4 acc[4][4] = {};

  int ar = tid >> 2;           // 0..63 (row within half-tile)
  int ac = (tid & 3) * 8;      // 0,8,16,24 (k within 32)
  const unsigned short* Ag = A + (size_t)(bm + ar) * K + ac;
  const unsigned short* Bg = Bt + (size_t)(bn + ar) * K + ac;
  unsigned short* AsW = &As[ar * 32 + ac];
  unsigned short* BsW = &Bs[ar * 32 + ac];

  for (int k0 = 0; k0 < K; k0 += 32) {
    gld_lds16(Ag + k0, AsW);
    gld_lds16(Ag + (size_t)64 * K + k0, AsW + 64 * 32);
    gld_lds16(Bg + k0, BsW);
    gld_lds16(Bg + (size_t)64 * K + k0, BsW + 64 * 32);
    __syncthreads();   // drains vmcnt (global_load_lds) + orders LDS
    frag8 af[4], bfr[4];
#pragma unroll
    for (int tm = 0; tm < 4; ++tm)
      af[tm] = *(const frag8*)&As[(wm + tm * 16 + r16) * 32 + quad * 8];
#pragma unroll
    for (int tn = 0; tn < 4; ++tn)
      bfr[tn] = *(const frag8*)&Bs[(wn + tn * 16 + r16) * 32 + quad * 8];
#pragma unroll
    for (int tm = 0; tm < 4; ++tm)
#pragma unroll
      for (int tn = 0; tn < 4; ++tn)
        acc[tm][tn] = __builtin_amdgcn_mfma_f32_16x16x32_bf16(
            af[tm], bfr[tn], acc[tm][tn], 0, 0, 0);
    __syncthreads();   // protect LDS before next stage
  }

  if (epi == 0) {
#pragma unroll
    for (int tm = 0; tm < 4; ++tm) {
#pragma unroll
      for (int tn = 0; tn < 4; ++tn) {
        int m0 = bm + wm + tm * 16 + quad * 4;
        int n = bn + wn + tn * 16 + r16;
#pragma unroll
        for (int r = 0; r < 4; ++r)
          outb[(size_t)(m0 + r) * N + n] = f2bf(gelu_fast(acc[tm][tn][r]));
      }
    }
  } else {
#pragma unroll
    for (int tm = 0; tm < 4; ++tm) {
#pragma unroll
      for (int tn = 0; tn < 4; ++tn) {
        int m0 = bm + wm + tm * 16 + quad * 4;
        int n = bn + wn + tn * 16 + r16;
#pragma unroll
        for (int r = 0; r < 4; ++r)
          outf[(size_t)(m0 + r) * N + n] =
              resid[(size_t)(m0 + r) * N + n] + acc[tm][tn][r];
      }
    }
  }
}

// ---------------------------------------------------------------------------
extern "C" void kernel_launch(void* const* d_in, const int* in_sizes, int n_in,
                              void* d_out, int out_size, void* d_ws,
                              size_t ws_size, hipStream_t stream) {
  const float* x = (const float*)d_in[0];
  const int* lengths = (const int*)d_in[1];
  const float* ln1_w = (const float*)d_in[2];
  const float* ln2_w = (const float*)d_in[3];
  const float* Wfc = (const float*)d_in[4];
  const float* Wproj = (const float*)d_in[5];
  float* out = (float*)d_out;   // doubles as the xres residual-stream buffer

  // Workspace layout — fixed ~52 MiB + act slice sized from ws_size.
  char* ws = (char*)d_ws;
  size_t off = 0;
  float2* stats = (float2*)(ws + off);
  off += (size_t)B_SZ * T_SZ * sizeof(float2);                  // 128 KiB
  float* csum = (float*)(ws + off);
  off += (size_t)B_SZ * NCHUNK * D_SZ * sizeof(float);          // 4 MiB
  unsigned short* wfcb = (unsigned short*)(ws + off);
  off += (size_t)D_SZ * H_SZ * sizeof(unsigned short);          // 8 MiB
  unsigned short* wprojb = (unsigned short*)(ws + off);
  off += (size_t)H_SZ * D_SZ * sizeof(unsigned short);          // 8 MiB
  unsigned short* h2 = (unsigned short*)(ws + off);
  off += (size_t)B_SZ * T_SZ * D_SZ * sizeof(unsigned short);   // 32 MiB
  unsigned short* act = (unsigned short*)(ws + off);            // slice buffer

  const int M = B_SZ * T_SZ;                       // 16384
  const size_t tileBytes = 128ull * H_SZ * sizeof(unsigned short);  // 1 MiB
  size_t avail = (ws_size > off) ? (ws_size - off) : 0;
  int sliceTiles = (int)(avail / tileBytes);
  if (sliceTiles < 1) sliceTiles = 1;              // last-resort (ws too small)
  int sliceM = sliceTiles * 128;
  if (sliceM > M) sliceM = M;

  ln_stats<<<B_SZ * T_SZ, 256, 0, stream>>>(x, stats);
  attn_phase1<<<B_SZ * NCHUNK, 256, 0, stream>>>(x, stats, lengths, ln1_w,
                                                 out, csum);
  chunk_scan<<<(B_SZ * D_SZ) / 256, 256, 0, stream>>>(csum);
  attn_phase2_ln2<<<B_SZ * T_SZ, 256, 0, stream>>>(out, csum, lengths, ln2_w, h2);
  transpose_f32_to_bf16<<<dim3(H_SZ / 32, D_SZ / 32), 256, 0, stream>>>(
      Wfc, wfcb, D_SZ, H_SZ);
  transpose_f32_to_bf16<<<dim3(D_SZ / 32, H_SZ / 32), 256, 0, stream>>>(
      Wproj, wprojb, H_SZ, D_SZ);

  for (int m0 = 0; m0 < M; m0 += sliceM) {
    int rows = (M - m0 < sliceM) ? (M - m0) : sliceM;
    // act = bf16(gelu(h2[m0:m0+rows] @ Wfc))
    gemm_bt<<<dim3(H_SZ / 128, rows / 128), 256, 0, stream>>>(
        h2 + (size_t)m0 * D_SZ, wfcb, H_SZ, D_SZ, nullptr, nullptr, act, 0);
    // out[m0:m0+rows] = out[m0:m0+rows] + act @ Wproj
    gemm_bt<<<dim3(D_SZ / 128, rows / 128), 256, 0, stream>>>(
        act, wprojb, D_SZ, H_SZ, out + (size_t)m0 * D_SZ,
        out + (size_t)m0 * D_SZ, nullptr, 1);
  }
}